// Round 5
// baseline (732.565 us; speedup 1.0000x reference)
//
#include <hip/hip_runtime.h>
#include <math.h>

#define BATCH  8192
#define D_IN   592
#define FBANKS 8
#define P1     147   // pool1 output length
#define P2     36    // pool2 output length
#define P1PAD  152   // padded row (16B-multiple stride, room for b128 over-read)
#define NW     4     // waves (rows) per block

// DIAGNOSTIC ROUND 2: identical to R3 except a register-only FMA delay tail on
// block 0, now 75k iters (measured 2.8us/1k iters => ~210us). R4's 30k-iter
// delay left fb_kernel at ~284us, 7us below the poison fills' top-5 cutoff.
// Goal: reveal fb_kernel's FETCH_SIZE/WRITE_SIZE to decide write-allocate-RMW
// (FETCH ~ 466MB) vs clean-traffic (FETCH ~ 20MB).

#define WAVE_SYNC() do { __builtin_amdgcn_wave_barrier(); asm volatile("" ::: "memory"); } while (0)

typedef float f4v __attribute__((ext_vector_type(4)));
static __device__ __forceinline__ void nt_store4(float* p, float a, float b,
                                                 float c, float d) {
    f4v t = {a, b, c, d};
    __builtin_nontemporal_store(t, (f4v*)p);
}

__global__ __launch_bounds__(256, 5) void fb_kernel(
    const float* __restrict__ x,
    const float* __restrict__ c1w, const float* __restrict__ c1b,
    const float* __restrict__ c2w, const float* __restrict__ c2b,
    const float* __restrict__ l1w, const float* __restrict__ l1b,
    const float* __restrict__ l2w, const float* __restrict__ l2b,
    const float* __restrict__ l3w, const float* __restrict__ l3b,
    float* __restrict__ outH, float* __restrict__ outXF,
    float* __restrict__ outXS, float* __restrict__ outF0)
{
    __shared__ __align__(16) float s_xa[NW][D_IN];        // 9472 B (= XS staging)
    __shared__ __align__(16) float s_oH[NW][D_IN];        // 9472 B (H staging)
    __shared__ __align__(16) float s_p1[NW][3][P1PAD];
    __shared__ __align__(16) float s_p2[NW][40];
    __shared__ __align__(16) float s_l1o[NW][20];

    const int tid  = threadIdx.x;
    const int wave = tid >> 6;
    const int lane = tid & 63;
    const int row  = blockIdx.x * NW + wave;
    const size_t blkrow = (size_t)blockIdx.x * NW;

    float* xa = s_xa[wave];
    const float* xrow = x + (size_t)row * D_IN;
    for (int i = lane; i < 148; i += 64) {
        *(float4*)&xa[4 * i] = *(const float4*)&xrow[4 * i];
    }
    WAVE_SYNC();

    const float negc2 = -0.028853900817779268f;   // -log2(e)/50

    for (int bank = 0; bank < FBANKS; ++bank) {
        float w1[3][3], b1[3], w2[3][3];
        #pragma unroll
        for (int c = 0; c < 3; ++c) {
            b1[c] = c1b[bank * 3 + c];
            #pragma unroll
            for (int k = 0; k < 3; ++k) {
                w1[c][k] = c1w[bank * 9 + c * 3 + k];
                w2[c][k] = c2w[bank * 9 + c * 3 + k];
            }
        }
        const float b2 = c2b[bank];

        for (int p = lane; p < P1; p += 64) {
            float4 a = *(const float4*)&xa[4 * p];
            float4 b = *(const float4*)&xa[4 * p + 4];
            float xv0 = a.x, xv1 = a.y, xv2 = a.z, xv3 = a.w;
            float xv4 = b.x, xv5 = b.y, xv6 = b.z;
            #pragma unroll
            for (int c = 0; c < 3; ++c) {
                float v0 = w1[c][0] * xv0 + w1[c][1] * xv1 + w1[c][2] * xv2;
                float v1 = w1[c][0] * xv2 + w1[c][1] * xv3 + w1[c][2] * xv4;
                float v2 = w1[c][0] * xv4 + w1[c][1] * xv5 + w1[c][2] * xv6;
                float m  = fmaxf(fmaxf(v0, v1), v2) + b1[c];
                s_p1[wave][c][p] = fmaxf(m, 0.0f);
            }
        }
        WAVE_SYNC();

        if (lane < P2) {
            const int q = lane;
            float acc0 = b2, acc1 = b2, acc2 = b2;
            #pragma unroll
            for (int c = 0; c < 3; ++c) {
                const float* r = s_p1[wave][c];
                float4 a = *(const float4*)&r[4 * q];
                float4 b = *(const float4*)&r[4 * q + 4];
                float v0 = a.x, v1 = a.y, v2 = a.z, v3 = a.w, v4 = b.x, v5 = b.y, v6 = b.z;
                acc0 += w2[c][0] * v0 + w2[c][1] * v1 + w2[c][2] * v2;
                acc1 += w2[c][0] * v2 + w2[c][1] * v3 + w2[c][2] * v4;
                acc2 += w2[c][0] * v4 + w2[c][1] * v5 + w2[c][2] * v6;
            }
            float mm = fmaxf(fmaxf(acc0, acc1), acc2);
            s_p2[wave][q] = fmaxf(mm, 0.0f);
        }
        WAVE_SYNC();

        if (lane < 20) {
            const float4* wr = (const float4*)(l1w + bank * 720 + lane * 36);
            float acc = l1b[bank * 20 + lane];
            #pragma unroll
            for (int k = 0; k < 9; ++k) {
                float4 w = wr[k];
                float4 v = *(const float4*)&s_p2[wave][4 * k];
                acc += w.x * v.x + w.y * v.y + w.z * v.z + w.w * v.w;
            }
            s_l1o[wave][lane] = fmaxf(acc, 0.0f);
        }
        WAVE_SYNC();

        float part = 0.0f;
        if (lane < 10) {
            const float4* wr = (const float4*)(l2w + bank * 200 + lane * 20);
            float acc = l2b[bank * 10 + lane];
            #pragma unroll
            for (int k = 0; k < 5; ++k) {
                float4 w = wr[k];
                float4 v = *(const float4*)&s_l1o[wave][4 * k];
                acc += w.x * v.x + w.y * v.y + w.z * v.z + w.w * v.w;
            }
            part = fmaxf(acc, 0.0f) * l3w[bank * 10 + lane];
        }
        part += __shfl_xor(part, 1);
        part += __shfl_xor(part, 2);
        part += __shfl_xor(part, 4);
        part += __shfl_xor(part, 8);
        float acc3 = __uint_as_float(__builtin_amdgcn_readfirstlane(__float_as_uint(part)))
                   + l3b[bank];
        float sig  = 1.0f / (1.0f + __expf(-acc3));
        float f0v  = (float)D_IN * sig;
        if (lane == 0) outF0[(size_t)bank * BATCH + row] = f0v;

        // ---- filter: stage H in LDS, keep xn (next x_aux) in registers ----
        float4 xn0, xn1, xn2 = {0.f, 0.f, 0.f, 0.f};
        {
            float4 xv = *(const float4*)&xa[4 * lane];
            float d0 = (float)(4 * lane) - f0v;
            float4 Hv;
            Hv.x = __builtin_amdgcn_exp2f(d0 * d0 * negc2);
            Hv.y = __builtin_amdgcn_exp2f((d0 + 1.f) * (d0 + 1.f) * negc2);
            Hv.z = __builtin_amdgcn_exp2f((d0 + 2.f) * (d0 + 2.f) * negc2);
            Hv.w = __builtin_amdgcn_exp2f((d0 + 3.f) * (d0 + 3.f) * negc2);
            *(float4*)&s_oH[wave][4 * lane] = Hv;
            xn0.x = xv.x - xv.x * Hv.x;  xn0.y = xv.y - xv.y * Hv.y;
            xn0.z = xv.z - xv.z * Hv.z;  xn0.w = xv.w - xv.w * Hv.w;
        }
        {
            const int e = 4 * (64 + lane);
            float4 xv = *(const float4*)&xa[e];
            float d0 = (float)e - f0v;
            float4 Hv;
            Hv.x = __builtin_amdgcn_exp2f(d0 * d0 * negc2);
            Hv.y = __builtin_amdgcn_exp2f((d0 + 1.f) * (d0 + 1.f) * negc2);
            Hv.z = __builtin_amdgcn_exp2f((d0 + 2.f) * (d0 + 2.f) * negc2);
            Hv.w = __builtin_amdgcn_exp2f((d0 + 3.f) * (d0 + 3.f) * negc2);
            *(float4*)&s_oH[wave][e] = Hv;
            xn1.x = xv.x - xv.x * Hv.x;  xn1.y = xv.y - xv.y * Hv.y;
            xn1.z = xv.z - xv.z * Hv.z;  xn1.w = xv.w - xv.w * Hv.w;
        }
        if (lane < 20) {
            const int e = 4 * (128 + lane);
            float4 xv = *(const float4*)&xa[e];
            float d0 = (float)e - f0v;
            float4 Hv;
            Hv.x = __builtin_amdgcn_exp2f(d0 * d0 * negc2);
            Hv.y = __builtin_amdgcn_exp2f((d0 + 1.f) * (d0 + 1.f) * negc2);
            Hv.z = __builtin_amdgcn_exp2f((d0 + 2.f) * (d0 + 2.f) * negc2);
            Hv.w = __builtin_amdgcn_exp2f((d0 + 3.f) * (d0 + 3.f) * negc2);
            *(float4*)&s_oH[wave][e] = Hv;
            xn2.x = xv.x - xv.x * Hv.x;  xn2.y = xv.y - xv.y * Hv.y;
            xn2.z = xv.z - xv.z * Hv.z;  xn2.w = xv.w - xv.w * Hv.w;
        }
        __syncthreads();

        {
            const size_t base = ((size_t)bank * BATCH + blkrow) * D_IN;
            const float* xf_ = &s_xa[0][0];
            const float* hf_ = &s_oH[0][0];
            {   const int u = tid;
                float4 xv = *(const float4*)&xf_[4 * u];
                float4 hv = *(const float4*)&hf_[4 * u];
                nt_store4((float*)&outXS[base + 4 * u], xv.x, xv.y, xv.z, xv.w);
                nt_store4((float*)&outH [base + 4 * u], hv.x, hv.y, hv.z, hv.w);
                nt_store4((float*)&outXF[base + 4 * u], xv.x * hv.x, xv.y * hv.y,
                                                        xv.z * hv.z, xv.w * hv.w);
            }
            {   const int u = tid + 256;
                float4 xv = *(const float4*)&xf_[4 * u];
                float4 hv = *(const float4*)&hf_[4 * u];
                nt_store4((float*)&outXS[base + 4 * u], xv.x, xv.y, xv.z, xv.w);
                nt_store4((float*)&outH [base + 4 * u], hv.x, hv.y, hv.z, hv.w);
                nt_store4((float*)&outXF[base + 4 * u], xv.x * hv.x, xv.y * hv.y,
                                                        xv.z * hv.z, xv.w * hv.w);
            }
            if (tid < 80) {
                const int u = tid + 512;
                float4 xv = *(const float4*)&xf_[4 * u];
                float4 hv = *(const float4*)&hf_[4 * u];
                nt_store4((float*)&outXS[base + 4 * u], xv.x, xv.y, xv.z, xv.w);
                nt_store4((float*)&outH [base + 4 * u], hv.x, hv.y, hv.z, hv.w);
                nt_store4((float*)&outXF[base + 4 * u], xv.x * hv.x, xv.y * hv.y,
                                                        xv.z * hv.z, xv.w * hv.w);
            }
        }
        __syncthreads();

        if (bank < FBANKS - 1) {
            *(float4*)&xa[4 * lane]        = xn0;
            *(float4*)&xa[4 * (64 + lane)] = xn1;
            if (lane < 20)
                *(float4*)&xa[4 * (128 + lane)] = xn2;
        }
        WAVE_SYNC();
    }

    // ---- DIAGNOSTIC delay: block 0 only, register-only, ~210us (75k iters
    //      at the measured 2.8us/1k). No memory ops => FETCH/WRITE stay true.
    if (blockIdx.x == 0) {
        float a0 = (float)tid * 1.000001f + 0.1f;
        float a1 = a0 + 0.5f, a2 = a0 + 0.25f, a3 = a0 + 0.125f;
        for (int it = 0; it < 75000; ++it) {
            a0 = __builtin_fmaf(a0, 1.0000001f, 1.0e-7f);
            a1 = __builtin_fmaf(a1, 1.0000001f, 1.0e-7f);
            a2 = __builtin_fmaf(a2, 1.0000001f, 1.0e-7f);
            a3 = __builtin_fmaf(a3, 1.0000001f, 1.0e-7f);
        }
        asm volatile("" :: "v"(a0), "v"(a1), "v"(a2), "v"(a3));
    }
}

extern "C" void kernel_launch(void* const* d_in, const int* in_sizes, int n_in,
                              void* d_out, int out_size, void* d_ws, size_t ws_size,
                              hipStream_t stream) {
    const float* x   = (const float*)d_in[0];
    const float* c1w = (const float*)d_in[1];
    const float* c1b = (const float*)d_in[2];
    const float* c2w = (const float*)d_in[3];
    const float* c2b = (const float*)d_in[4];
    const float* l1w = (const float*)d_in[5];
    const float* l1b = (const float*)d_in[6];
    const float* l2w = (const float*)d_in[7];
    const float* l2b = (const float*)d_in[8];
    const float* l3w = (const float*)d_in[9];
    const float* l3b = (const float*)d_in[10];

    float* out = (float*)d_out;
    const size_t plane = (size_t)FBANKS * BATCH * D_IN;
    float* outH  = out;
    float* outXF = out + plane;
    float* outXS = out + 2 * plane;
    float* outF0 = out + 3 * plane;

    dim3 grid(BATCH / NW);
    dim3 block(256);
    fb_kernel<<<grid, block, 0, stream>>>(x, c1w, c1b, c2w, c2b,
                                          l1w, l1b, l2w, l2b, l3w, l3b,
                                          outH, outXF, outXS, outF0);
}

// Round 6
// 526.991 us; speedup vs baseline: 1.3901x; 1.3901x over previous
//
#include <hip/hip_runtime.h>
#include <math.h>

#define BATCH  8192
#define D_IN   592
#define FBANKS 8
#define P1     147   // pool1 output length
#define P2     36    // pool2 output length
#define P1PAD  152   // padded row (16B-multiple stride, room for b128 over-read)
#define NW     4     // waves (rows) per block in the chain kernel
#define PLANE  ((size_t)BATCH * D_IN)

// Two-dispatch split (R5 counters: traffic is clean -- WRITE=455MB, FETCH=9.6MB
// -- but effective BW only ~2.4TB/s and blocks are ~95% stalled).
// K1 fb_chain: serial conv/MLP chain only, f0 -> outF0 (doubles as handoff).
//   17KB LDS -> 8 blocks/CU, all 2048 blocks resident. No wide stores.
// K2 fb_stream: pure streaming. Each thread owns 3 fixed float4-units, holds
//   xa in registers across the bank loop, writes 3 monotonic fill-shaped
//   streams per bank. No LDS, no barriers. Measures chain vs store-rate
//   decisively via per-dispatch durations.

#define WAVE_SYNC() do { __builtin_amdgcn_wave_barrier(); asm volatile("" ::: "memory"); } while (0)

typedef float f4v __attribute__((ext_vector_type(4)));
static __device__ __forceinline__ void nt_store4p(float* p, float a, float b,
                                                  float c, float d) {
    f4v t = {a, b, c, d};
    __builtin_nontemporal_store(t, (f4v*)p);
}

// ========================= K1: chain-only =========================
__global__ __launch_bounds__(256, 8) void fb_chain(
    const float* __restrict__ x,
    const float* __restrict__ c1w, const float* __restrict__ c1b,
    const float* __restrict__ c2w, const float* __restrict__ c2b,
    const float* __restrict__ l1w, const float* __restrict__ l1b,
    const float* __restrict__ l2w, const float* __restrict__ l2b,
    const float* __restrict__ l3w, const float* __restrict__ l3b,
    float* __restrict__ outF0)
{
    __shared__ __align__(16) float s_xa[NW][D_IN];
    __shared__ __align__(16) float s_p1[NW][3][P1PAD];
    __shared__ __align__(16) float s_p2[NW][40];
    __shared__ __align__(16) float s_l1o[NW][20];
    // LDS = 17,008 B -> 8+ blocks/CU

    const int tid  = threadIdx.x;
    const int wave = tid >> 6;
    const int lane = tid & 63;
    const int row  = blockIdx.x * NW + wave;

    float* xa = s_xa[wave];
    const float* xrow = x + (size_t)row * D_IN;
    for (int i = lane; i < 148; i += 64) {
        *(float4*)&xa[4 * i] = *(const float4*)&xrow[4 * i];
    }
    WAVE_SYNC();

    const float negc2 = -0.028853900817779268f;   // -log2(e)/50

    for (int bank = 0; bank < FBANKS; ++bank) {
        float w1[3][3], b1[3], w2[3][3];
        #pragma unroll
        for (int c = 0; c < 3; ++c) {
            b1[c] = c1b[bank * 3 + c];
            #pragma unroll
            for (int k = 0; k < 3; ++k) {
                w1[c][k] = c1w[bank * 9 + c * 3 + k];
                w2[c][k] = c2w[bank * 9 + c * 3 + k];
            }
        }
        const float b2 = c2b[bank];

        for (int p = lane; p < P1; p += 64) {
            float4 a = *(const float4*)&xa[4 * p];
            float4 b = *(const float4*)&xa[4 * p + 4];
            float xv0 = a.x, xv1 = a.y, xv2 = a.z, xv3 = a.w;
            float xv4 = b.x, xv5 = b.y, xv6 = b.z;
            #pragma unroll
            for (int c = 0; c < 3; ++c) {
                float v0 = w1[c][0] * xv0 + w1[c][1] * xv1 + w1[c][2] * xv2;
                float v1 = w1[c][0] * xv2 + w1[c][1] * xv3 + w1[c][2] * xv4;
                float v2 = w1[c][0] * xv4 + w1[c][1] * xv5 + w1[c][2] * xv6;
                float m  = fmaxf(fmaxf(v0, v1), v2) + b1[c];
                s_p1[wave][c][p] = fmaxf(m, 0.0f);
            }
        }
        WAVE_SYNC();

        if (lane < P2) {
            const int q = lane;
            float acc0 = b2, acc1 = b2, acc2 = b2;
            #pragma unroll
            for (int c = 0; c < 3; ++c) {
                const float* r = s_p1[wave][c];
                float4 a = *(const float4*)&r[4 * q];
                float4 b = *(const float4*)&r[4 * q + 4];
                float v0 = a.x, v1 = a.y, v2 = a.z, v3 = a.w, v4 = b.x, v5 = b.y, v6 = b.z;
                acc0 += w2[c][0] * v0 + w2[c][1] * v1 + w2[c][2] * v2;
                acc1 += w2[c][0] * v2 + w2[c][1] * v3 + w2[c][2] * v4;
                acc2 += w2[c][0] * v4 + w2[c][1] * v5 + w2[c][2] * v6;
            }
            float mm = fmaxf(fmaxf(acc0, acc1), acc2);
            s_p2[wave][q] = fmaxf(mm, 0.0f);
        }
        WAVE_SYNC();

        if (lane < 20) {
            const float4* wr = (const float4*)(l1w + bank * 720 + lane * 36);
            float acc = l1b[bank * 20 + lane];
            #pragma unroll
            for (int k = 0; k < 9; ++k) {
                float4 w = wr[k];
                float4 v = *(const float4*)&s_p2[wave][4 * k];
                acc += w.x * v.x + w.y * v.y + w.z * v.z + w.w * v.w;
            }
            s_l1o[wave][lane] = fmaxf(acc, 0.0f);
        }
        WAVE_SYNC();

        float part = 0.0f;
        if (lane < 10) {
            const float4* wr = (const float4*)(l2w + bank * 200 + lane * 20);
            float acc = l2b[bank * 10 + lane];
            #pragma unroll
            for (int k = 0; k < 5; ++k) {
                float4 w = wr[k];
                float4 v = *(const float4*)&s_l1o[wave][4 * k];
                acc += w.x * v.x + w.y * v.y + w.z * v.z + w.w * v.w;
            }
            part = fmaxf(acc, 0.0f) * l3w[bank * 10 + lane];
        }
        part += __shfl_xor(part, 1);
        part += __shfl_xor(part, 2);
        part += __shfl_xor(part, 4);
        part += __shfl_xor(part, 8);
        float acc3 = __uint_as_float(__builtin_amdgcn_readfirstlane(__float_as_uint(part)))
                   + l3b[bank];
        float sig  = 1.0f / (1.0f + __expf(-acc3));
        float f0v  = (float)D_IN * sig;
        if (lane == 0) outF0[(size_t)bank * BATCH + row] = f0v;

        // xa recurrence in LDS only; bank 7's update is dead (K2 replays all)
        if (bank < FBANKS - 1) {
            for (int i = lane; i < 148; i += 64) {
                float4 xv = *(const float4*)&xa[4 * i];
                float d0 = (float)(4 * i) - f0v;
                float h0 = __builtin_amdgcn_exp2f(d0 * d0 * negc2);
                float h1 = __builtin_amdgcn_exp2f((d0 + 1.f) * (d0 + 1.f) * negc2);
                float h2 = __builtin_amdgcn_exp2f((d0 + 2.f) * (d0 + 2.f) * negc2);
                float h3 = __builtin_amdgcn_exp2f((d0 + 3.f) * (d0 + 3.f) * negc2);
                float4 xn;
                xn.x = xv.x - xv.x * h0;  xn.y = xv.y - xv.y * h1;
                xn.z = xv.z - xv.z * h2;  xn.w = xv.w - xv.w * h3;
                *(float4*)&xa[4 * i] = xn;
            }
        }
        WAVE_SYNC();
    }
}

// ========================= K2: streaming replay =========================
#define K2_BLOCKS 2048
#define K2_GSZ    (K2_BLOCKS * 256)          // 524,288 threads
#define NUNITS    (BATCH * 148)              // 1,212,416 float4 units

static __device__ __forceinline__ void bank_step(float4& xa, float ebase, float f0v,
                                                 float* pH, float* pXF, float* pXS) {
    const float negc2 = -0.028853900817779268f;
    float d0 = ebase - f0v;
    float h0 = __builtin_amdgcn_exp2f(d0 * d0 * negc2);
    float h1 = __builtin_amdgcn_exp2f((d0 + 1.f) * (d0 + 1.f) * negc2);
    float h2 = __builtin_amdgcn_exp2f((d0 + 2.f) * (d0 + 2.f) * negc2);
    float h3 = __builtin_amdgcn_exp2f((d0 + 3.f) * (d0 + 3.f) * negc2);
    float xf0 = xa.x * h0, xf1 = xa.y * h1, xf2 = xa.z * h2, xf3 = xa.w * h3;
    nt_store4p(pXS, xa.x, xa.y, xa.z, xa.w);   // x_aux BEFORE filtering
    nt_store4p(pH,  h0, h1, h2, h3);
    nt_store4p(pXF, xf0, xf1, xf2, xf3);
    xa.x -= xf0;  xa.y -= xf1;  xa.z -= xf2;  xa.w -= xf3;
}

__global__ __launch_bounds__(256, 4) void fb_stream(
    const float* __restrict__ x, const float* __restrict__ f0t,
    float* __restrict__ outH, float* __restrict__ outXF,
    float* __restrict__ outXS)
{
    const int gtid = blockIdx.x * 256 + threadIdx.x;
    // three fixed units per thread (u2 partial: 2*GSZ=1,048,576 < NUNITS)
    const int u0 = gtid;
    const int u1 = gtid + K2_GSZ;
    const int u2 = gtid + 2 * K2_GSZ;
    const bool a2 = (u2 < NUNITS);

    const int r0 = u0 / 148, i0 = u0 - 148 * r0;
    const int r1 = u1 / 148, i1 = u1 - 148 * r1;
    const int r2i = a2 ? u2 : 0;
    const int r2 = r2i / 148, i2 = r2i - 148 * r2;

    const float e0 = (float)(4 * i0);
    const float e1 = (float)(4 * i1);
    const float e2 = (float)(4 * i2);

    float4 xa0 = *(const float4*)&x[(size_t)r0 * D_IN + 4 * i0];
    float4 xa1 = *(const float4*)&x[(size_t)r1 * D_IN + 4 * i1];
    float4 xa2 = *(const float4*)&x[(size_t)r2 * D_IN + 4 * i2];

    const size_t o0 = (size_t)r0 * D_IN + 4 * i0;
    const size_t o1 = (size_t)r1 * D_IN + 4 * i1;
    const size_t o2 = (size_t)r2 * D_IN + 4 * i2;

    #pragma unroll
    for (int b = 0; b < FBANKS; ++b) {
        const size_t sb = (size_t)b * PLANE;
        const float f00 = f0t[b * BATCH + r0];
        const float f01 = f0t[b * BATCH + r1];
        const float f02 = f0t[b * BATCH + r2];
        bank_step(xa0, e0, f00, &outH[sb + o0], &outXF[sb + o0], &outXS[sb + o0]);
        bank_step(xa1, e1, f01, &outH[sb + o1], &outXF[sb + o1], &outXS[sb + o1]);
        if (a2)
            bank_step(xa2, e2, f02, &outH[sb + o2], &outXF[sb + o2], &outXS[sb + o2]);
    }
}

extern "C" void kernel_launch(void* const* d_in, const int* in_sizes, int n_in,
                              void* d_out, int out_size, void* d_ws, size_t ws_size,
                              hipStream_t stream) {
    const float* x   = (const float*)d_in[0];
    const float* c1w = (const float*)d_in[1];
    const float* c1b = (const float*)d_in[2];
    const float* c2w = (const float*)d_in[3];
    const float* c2b = (const float*)d_in[4];
    const float* l1w = (const float*)d_in[5];
    const float* l1b = (const float*)d_in[6];
    const float* l2w = (const float*)d_in[7];
    const float* l2b = (const float*)d_in[8];
    const float* l3w = (const float*)d_in[9];
    const float* l3b = (const float*)d_in[10];

    float* out = (float*)d_out;
    const size_t plane = (size_t)FBANKS * BATCH * D_IN;
    float* outH  = out;
    float* outXF = out + plane;
    float* outXS = out + 2 * plane;
    float* outF0 = out + 3 * plane;

    fb_chain<<<dim3(BATCH / NW), dim3(256), 0, stream>>>(
        x, c1w, c1b, c2w, c2b, l1w, l1b, l2w, l2b, l3w, l3b, outF0);
    fb_stream<<<dim3(K2_BLOCKS), dim3(256), 0, stream>>>(
        x, outF0, outH, outXF, outXS);
}